// Round 4
// baseline (210.168 us; speedup 1.0000x reference)
//
#include <hip/hip_runtime.h>
#include <math.h>

#define BATCH 32
#define CH    3
#define H     512
#define W     512
#define KWIN  15
#define PAD   7
#define TH    8                 // output rows per block
#define NR    (TH + KWIN - 1)   // 22 input rows per tile

static __device__ __forceinline__ float4 min4(float4 a, float4 b) {
    float4 r;
    r.x = fminf(a.x, b.x); r.y = fminf(a.y, b.y);
    r.z = fminf(a.z, b.z); r.w = fminf(a.w, b.w);
    return r;
}

// Fused dark-channel + 15x15 min-pool. Thread = 4 columns (float4).
// All 66 global loads are unconditional (clamped row index) and issued in
// three independent batches of 22 -> high memory-level parallelism.
__global__ __launch_bounds__(128, 3) void dcp_fused3(const float* __restrict__ I,
                                                     float* __restrict__ out) {
    const int b  = blockIdx.y;
    const int y0 = blockIdx.x * TH;
    const int t  = threadIdx.x;
    const int x  = t * 4;                    // this thread's 4 columns

    __shared__ float tile[TH][W + 16];       // v-min rows; cols offset by 8 (16B-aligned halo)

    const float* base = I + (size_t)b * CH * H * W;

    float4 v[NR];                            // channel-min of rows y0-7 .. y0+14

    // Batch 1: channel 0 (22 independent b128 loads)
    #pragma unroll
    for (int i = 0; i < NR; ++i) {
        const int y = min(max(y0 - PAD + i, 0), H - 1);
        v[i] = *(const float4*)(base + ((size_t)0 * H + y) * W + x);
    }
    // Batch 2: channel 1
    #pragma unroll
    for (int i = 0; i < NR; ++i) {
        const int y = min(max(y0 - PAD + i, 0), H - 1);
        const float4 c = *(const float4*)(base + ((size_t)1 * H + y) * W + x);
        v[i] = min4(v[i], c);
    }
    // Batch 3: channel 2
    #pragma unroll
    for (int i = 0; i < NR; ++i) {
        const int y = min(max(y0 - PAD + i, 0), H - 1);
        const float4 c = *(const float4*)(base + ((size_t)2 * H + y) * W + x);
        v[i] = min4(v[i], c);
    }
    // OOB rows -> +inf (only first/last y-tile have any)
    if (blockIdx.x == 0 || blockIdx.x == gridDim.x - 1) {
        const float4 inf4 = make_float4(INFINITY, INFINITY, INFINITY, INFINITY);
        #pragma unroll
        for (int i = 0; i < NR; ++i) {
            const int y = y0 - PAD + i;
            if (y < 0 || y >= H) v[i] = inf4;
        }
    }

    // Vertical 15-min via van Herk: P[k] = min(v[15..15+k]); U folds v[14]..v[0].
    float4 P[PAD];
    P[0] = v[15];
    #pragma unroll
    for (int k = 1; k < PAD; ++k) P[k] = min4(P[k - 1], v[15 + k]);
    float4 U = v[14];
    #pragma unroll
    for (int i = 13; i >= 8; --i) U = min4(U, v[i]);
    #pragma unroll
    for (int i = PAD; i >= 0; --i) {
        U = min4(U, v[i]);
        const float4 o = (i > 0) ? min4(U, P[i - 1]) : U;
        *(float4*)&tile[i][8 + x] = o;       // byte offset 32+16t: aligned b128
    }

    // +inf column halo: cols -8..-1 and 512..519 (8 each side per row)
    if (t < 64) {
        const int r = t >> 3, c = t & 7;
        tile[r][c]           = INFINITY;
        tile[r][8 + W + c]   = INFINITY;
    }
    __syncthreads();                         // the only barrier

    // Horizontal 15-min: 5 aligned b128 reads cover dark cols x-8 .. x+11.
    #pragma unroll
    for (int r = 0; r < TH; ++r) {
        float4 w0 = *(const float4*)&tile[r][x];
        float4 w1 = *(const float4*)&tile[r][x + 4];
        float4 w2 = *(const float4*)&tile[r][x + 8];
        float4 w3 = *(const float4*)&tile[r][x + 12];
        float4 w4 = *(const float4*)&tile[r][x + 16];
        // common = min over cols x-4 .. x+7 (w1,w2,w3)
        float4 q = min4(min4(w1, w2), w3);
        const float common = fminf(fminf(q.x, q.y), fminf(q.z, q.w));
        const float a   = fminf(w0.z, w0.w);        // cols x-6,x-5
        const float L0  = fminf(w0.y, a);           // cols x-7..x-5
        const float r01 = fminf(w4.x, w4.y);        // cols x+8,x+9
        const float r012= fminf(r01, w4.z);         // cols x+8..x+10
        float4 o;
        o.x = fminf(common, L0);                    // x-7..x+7
        o.y = fminf(fminf(common, a), w4.x);        // x-6..x+8
        o.z = fminf(fminf(common, w0.w), r01);      // x-5..x+9
        o.w = fminf(common, r012);                  // x-4..x+10
        *(float4*)(out + ((size_t)b * H + y0 + r) * W + x) = o;
    }
}

extern "C" void kernel_launch(void* const* d_in, const int* in_sizes, int n_in,
                              void* d_out, int out_size, void* d_ws, size_t ws_size,
                              hipStream_t stream) {
    const float* I = (const float*)d_in[0];
    // d_in[1] is k == 15, hard-coded (KWIN/PAD)
    float* out = (float*)d_out;
    dcp_fused3<<<dim3(H / TH, BATCH), dim3(128), 0, stream>>>(I, out);
}

// Round 5
// 198.206 us; speedup vs baseline: 1.0604x; 1.0604x over previous
//
#include <hip/hip_runtime.h>
#include <math.h>

#define BATCH 32
#define CH    3
#define H     512
#define W     512
#define KWIN  15
#define PAD   7
#define TH    8                 // output rows per block
#define NR    (TH + KWIN - 1)   // 22 input rows per tile

static __device__ __forceinline__ float2 min2(float2 a, float2 b) {
    float2 r;
    r.x = fminf(a.x, b.x);
    r.y = fminf(a.y, b.y);
    return r;
}

// Fused dark-channel + 15x15 min-pool, vertical-first separable order.
// float2 per thread; 3 batches of 22 independent b64 loads (clamped row
// index, OOB fixed up after) for memory-level parallelism without spills.
// LDS traffic kept at b64 width (b128 LDS reads measured conflict-heavy on
// gfx950 in R4: 3.5M conflicts vs 262k for the same pattern at b64).
__global__ __launch_bounds__(256, 4) void dcp_fused4(const float* __restrict__ I,
                                                     float* __restrict__ out) {
    const int b  = blockIdx.y;
    const int y0 = blockIdx.x * TH;
    const int t  = threadIdx.x;
    const int x  = t * 2;                       // this thread's 2 columns

    __shared__ float tile[TH][W + 2 * PAD + 2]; // v-min rows; halo [0..6], data at 7+x

    const float* base = I + (size_t)b * CH * H * W;

    float2 v[NR];                               // channel-min of rows y0-7 .. y0+14

    // Batch 1: channel 0 — 22 independent b64 loads
    #pragma unroll
    for (int i = 0; i < NR; ++i) {
        const int y = min(max(y0 - PAD + i, 0), H - 1);
        v[i] = *(const float2*)(base + ((size_t)0 * H + y) * W + x);
    }
    // Batch 2: channel 1
    #pragma unroll
    for (int i = 0; i < NR; ++i) {
        const int y = min(max(y0 - PAD + i, 0), H - 1);
        v[i] = min2(v[i], *(const float2*)(base + ((size_t)1 * H + y) * W + x));
    }
    // Batch 3: channel 2
    #pragma unroll
    for (int i = 0; i < NR; ++i) {
        const int y = min(max(y0 - PAD + i, 0), H - 1);
        v[i] = min2(v[i], *(const float2*)(base + ((size_t)2 * H + y) * W + x));
    }
    // OOB rows -> +inf (only first/last y-tile have any)
    if (blockIdx.x == 0 || blockIdx.x == gridDim.x - 1) {
        const float2 inf2 = make_float2(INFINITY, INFINITY);
        #pragma unroll
        for (int i = 0; i < NR; ++i) {
            const int y = y0 - PAD + i;
            if (y < 0 || y >= H) v[i] = inf2;
        }
    }

    // Vertical 15-min via van Herk: P[k] = min(v[15..15+k]); U folds v[14]..v[0].
    float2 P[PAD];
    P[0] = v[15];
    #pragma unroll
    for (int k = 1; k < PAD; ++k) P[k] = min2(P[k - 1], v[15 + k]);
    float2 U = v[14];
    #pragma unroll
    for (int i = 13; i >= 8; --i) U = min2(U, v[i]);
    #pragma unroll
    for (int i = PAD; i >= 0; --i) {
        U = min2(U, v[i]);
        const float2 o = (i > 0) ? min2(U, P[i - 1]) : U;
        *(float2*)&tile[i][PAD + x] = o;        // byte offset 28+8t... index 7+x
    }

    // +inf column halo: padded indices 0..6 and 519..525
    if (t < PAD) {
        #pragma unroll
        for (int r = 0; r < TH; ++r) tile[r][t] = INFINITY;
    } else if (t < 2 * PAD) {
        #pragma unroll
        for (int r = 0; r < TH; ++r) tile[r][W + t] = INFINITY;
    }
    __syncthreads();                            // the only barrier

    // Horizontal 15-min: 8 b64 reads at even indices (conflict-cheap),
    // covering padded indices x .. x+15 = dark cols x-7 .. x+8.
    #pragma unroll
    for (int r = 0; r < TH; ++r) {
        float2 w[8];
        #pragma unroll
        for (int j = 0; j < 8; ++j) w[j] = *(const float2*)&tile[r][x + 2 * j];
        float m = fminf(w[0].y, w[7].x);
        #pragma unroll
        for (int j = 1; j < 7; ++j) m = fminf(m, fminf(w[j].x, w[j].y));
        float2 o;
        o.x = fminf(m, w[0].x);                 // cols x-7..x+7
        o.y = fminf(m, w[7].y);                 // cols x-6..x+8
        *(float2*)(out + ((size_t)b * H + y0 + r) * W + x) = o;
    }
}

extern "C" void kernel_launch(void* const* d_in, const int* in_sizes, int n_in,
                              void* d_out, int out_size, void* d_ws, size_t ws_size,
                              hipStream_t stream) {
    const float* I = (const float*)d_in[0];
    // d_in[1] is k == 15, hard-coded (KWIN/PAD)
    float* out = (float*)d_out;
    dcp_fused4<<<dim3(H / TH, BATCH), dim3(256), 0, stream>>>(I, out);
}

// Round 6
// 166.397 us; speedup vs baseline: 1.2631x; 1.1912x over previous
//
#include <hip/hip_runtime.h>
#include <math.h>

#define BATCH 32
#define CH    3
#define H     512
#define W     512
#define KWIN  15
#define PAD   7
#define T2    16   // output rows per thread in pass 2

static __device__ __forceinline__ float2 min2(float2 a, float2 b) {
    float2 r;
    r.x = fminf(a.x, b.x);
    r.y = fminf(a.y, b.y);
    return r;
}

// Pass 1: channel-min + horizontal 15-min. One block per (b, row), float2/thread.
// LDS reads use the 8x ds_read_b64 even-index pattern (2-way conflicts = free;
// scalar stride-2 reads measured 4-way, b128 reads measured 8-way on gfx950).
// NO __launch_bounds__: hints twice produced pathological allocs (R3: 20 VGPR
// serialized loads; R5: 64 VGPR + 90 MB scratch spill).
__global__ void dcp_p1(const float* __restrict__ I, float* __restrict__ tmp) {
    const int bh = blockIdx.x;          // b*H + h
    const int b  = bh >> 9;
    const int h  = bh & (H - 1);
    const int t  = threadIdx.x;
    const int x  = t * 2;

    __shared__ float s[W + 2 * PAD + 2];   // dark row at s[7+i]; +inf halo both sides

    const float* p = I + ((size_t)b * CH * H + h) * W + x;
    const float2 a0 = *(const float2*)(p);
    const float2 a1 = *(const float2*)(p + (size_t)H * W);
    const float2 a2 = *(const float2*)(p + (size_t)2 * H * W);
    const float2 d  = min2(min2(a0, a1), a2);
    s[PAD + x]     = d.x;
    s[PAD + x + 1] = d.y;
    if (t < PAD) {
        s[t]           = INFINITY;
        s[PAD + W + t] = INFINITY;
    }
    __syncthreads();

    // 8 aligned b64 reads cover padded idx x..x+15 = dark cols x-7..x+8
    float2 w[8];
    #pragma unroll
    for (int j = 0; j < 8; ++j) w[j] = *(const float2*)&s[x + 2 * j];
    float m = fminf(w[0].y, w[7].x);
    #pragma unroll
    for (int j = 1; j < 7; ++j) m = fminf(m, fminf(w[j].x, w[j].y));
    float2 o;
    o.x = fminf(m, w[0].x);             // window cols x-7..x+7
    o.y = fminf(m, w[7].y);             // window cols x-6..x+8
    *(float2*)(tmp + ((size_t)b * H + h) * W + x) = o;
}

// Pass 2: vertical 15-min, van Herk over T2=16 output rows. Thread = 2 columns.
// Window for output r (v-idx r..r+14) splits at v-idx 15:
//   S0[r] = min(v[r..14]) streamed descending; P1[j] = min(v[15..15+j]) array.
__global__ void dcp_p2(const float* __restrict__ tmp, float* __restrict__ out) {
    const int x  = threadIdx.x * 2;     // 256 threads cover all 512 cols
    const int y0 = blockIdx.x * T2;
    const int b  = blockIdx.y;

    const float* col = tmp + (size_t)b * H * W + x;
    float*       o   = out + (size_t)b * H * W + x;

    // Phase 1: seg1 = v[15..29] = rows y0+8 .. y0+22 (clamped; inf fixup last block)
    float2 vb[KWIN];
    #pragma unroll
    for (int j = 0; j < KWIN; ++j) {
        const int y = min(y0 + 8 + j, H - 1);
        vb[j] = *(const float2*)(col + (size_t)y * W);
    }
    if (y0 + 8 + KWIN - 1 >= H) {       // block-uniform (last y-block only)
        const float2 inf2 = make_float2(INFINITY, INFINITY);
        #pragma unroll
        for (int j = 0; j < KWIN; ++j)
            if (y0 + 8 + j >= H) vb[j] = inf2;
    }
    float2 P[KWIN];
    P[0] = vb[0];
    #pragma unroll
    for (int j = 1; j < KWIN; ++j) P[j] = min2(P[j - 1], vb[j]);
    *(float2*)(o + (size_t)(y0 + 15) * W) = P[14];   // o[15] = min(v[15..29])

    // Phase 2: seg0 = v[0..14] = rows y0-7 .. y0+7 (clamped; inf fixup first block)
    float2 va[KWIN];
    #pragma unroll
    for (int i = 0; i < KWIN; ++i) {
        const int y = max(y0 - PAD + i, 0);
        va[i] = *(const float2*)(col + (size_t)y * W);
    }
    if (y0 == 0) {                      // block-uniform
        const float2 inf2 = make_float2(INFINITY, INFINITY);
        #pragma unroll
        for (int i = 0; i < PAD; ++i) va[i] = inf2;
    }
    float2 run = va[14];
    *(float2*)(o + (size_t)(y0 + 14) * W) = min2(run, P[13]);
    #pragma unroll
    for (int r = 13; r >= 1; --r) {
        run = min2(run, va[r]);
        *(float2*)(o + (size_t)(y0 + r) * W) = min2(run, P[r - 1]);
    }
    run = min2(run, va[0]);
    *(float2*)(o + (size_t)y0 * W) = run;
}

extern "C" void kernel_launch(void* const* d_in, const int* in_sizes, int n_in,
                              void* d_out, int out_size, void* d_ws, size_t ws_size,
                              hipStream_t stream) {
    const float* I = (const float*)d_in[0];
    // d_in[1] is k == 15, hard-coded (KWIN/PAD)
    float* out = (float*)d_out;
    float* tmp = (float*)d_ws;          // 33.6 MB scratch

    dcp_p1<<<dim3(BATCH * H), dim3(256), 0, stream>>>(I, tmp);
    dcp_p2<<<dim3(H / T2, BATCH), dim3(256), 0, stream>>>(tmp, out);
}